// Round 5
// baseline (23.471 us; speedup 1.0000x reference)
//
#include <hip/hip_runtime.h>
#include <hip/hip_fp16.h>

// NEAT sparse MLP fwd. LAYER_SIZES=[256,512,512,512,512,64], FAN_IN=32, BATCH=2048.
// OFFSETS=[0,256,768,1280,1792,2304,2368]; E_TOT=67584.
//
// R5: occupancy fix. 1024-thread blocks (16 waves/CU, was 8): thread = (node n,
// half h); each half gathers 16 of the node's 32 edges (ds_read_b128 serves 8
// batch rows), halves combined via LDS float8 partial + add by h=0. Packed 4 B
// edge records (off:16 | w_f16:16), per-(group,chunk,half) transposed so each
// wave's record loads are one coalesced b128. f16 acts [node][8] in LDS.

typedef _Float16 half8_t  __attribute__((ext_vector_type(8)));
typedef float    float8_t __attribute__((ext_vector_type(8)));

constexpr int TB    = 8;
constexpr int BLOCK = 1024;
constexpr int E_TOT = 67584;

__global__ void pack_edges(const int* __restrict__ src, const float* __restrict__ w,
                           unsigned* __restrict__ rec)
{
    const int o = blockIdx.x * 256 + threadIdx.x;
    if (o >= E_TOT) return;
    int eid, offPrev;
    if (o < 65536) {
        // 512-wide layers. int4 record idx t = ((g*4 + c)*2 + h)*64 + i
        // covers edges eid = e0 + (g*64+i)*32 + h*16 + c*4 + q.
        const int layer = o >> 14;            // 0..3
        const int e0    = layer << 14;
        offPrev = (layer == 0) ? 0 : (256 + (layer - 1) * 512);
        const int ol = o - e0;
        const int q  = ol & 3;
        const int t  = ol >> 2;
        const int i  = t & 63;
        const int t2 = t >> 6;
        const int h  = t2 & 1;
        const int t3 = t2 >> 1;
        const int c  = t3 & 3;
        const int g  = t3 >> 2;
        eid = e0 + (g * 64 + i) * 32 + h * 16 + c * 4 + q;
    } else {
        // layer 5: int4 record idx r = c*64+n covers eid = n*32 + c*4 + q.
        offPrev = 1792;
        const int ol = o - 65536;
        const int q = ol & 3, r = ol >> 2;
        const int c = r >> 6, n = r & 63;
        eid = 65536 + n * 32 + c * 4 + q;
    }
    const unsigned off = (unsigned)(src[eid] - offPrev) * (TB * 2);  // byte off, [node][8] f16
    const unsigned hw  = (unsigned)__half_as_ushort(__float2half(w[eid]));
    rec[o] = off | (hw << 16);
}

__device__ __forceinline__ float sigmoidf(float s)
{
    return __fdividef(1.0f, 1.0f + __expf(-s));
}

template<bool PACKED>
__global__ __launch_bounds__(BLOCK, 1) void neat_fwd(
    const float* __restrict__ x,
    const float* __restrict__ w,
    const int*   __restrict__ src,
    const int4*  __restrict__ rp,      // packed records as int4 (4 edges)
    float*       __restrict__ out)
{
    __shared__ __align__(16) _Float16 bufA[512 * TB];   // 8 KB
    __shared__ __align__(16) _Float16 bufB[512 * TB];   // 8 KB
    __shared__ __align__(16) float scratch[512 * 12];   // 24 KB, stride-12 pad

    const int tid    = threadIdx.x;
    const int n      = tid & 511;      // node
    const int h      = tid >> 9;       // edge half
    const int batch0 = blockIdx.x * TB;

    // Stage input layer as f16 [node][8]: 512 threads, one float4 each.
    if (tid < 512) {
        const int r  = tid >> 6;          // 0..7
        const int c4 = (tid & 63) * 4;    // node base
        const float4 v = *(const float4*)(x + (size_t)(batch0 + r) * 256 + c4);
        bufA[(c4 + 0) * TB + r] = (_Float16)v.x;
        bufA[(c4 + 1) * TB + r] = (_Float16)v.y;
        bufA[(c4 + 2) * TB + r] = (_Float16)v.z;
        bufA[(c4 + 3) * TB + r] = (_Float16)v.w;
    }
    __syncthreads();

    _Float16* prev = bufA;
    _Float16* cur  = bufB;

    const int g = n >> 6, i = n & 63;
    const int base = g * 512 + h * 64 + i;   // int4 idx; chunk c adds c*128

#define EDGE(RR, ACC)                                                          \
    do {                                                                       \
        const unsigned rr = (unsigned)(RR);                                    \
        const float wf = __half2float(__ushort_as_half((unsigned short)(rr >> 16))); \
        const half8_t a = *(const half8_t*)(pv + (rr & 0xffffu));              \
        _Pragma("unroll")                                                      \
        for (int k = 0; k < 8; ++k)                                            \
            ACC[k] = fmaf((float)a[k], wf, ACC[k]);                            \
    } while (0)

#define EDGE_RAW(SRCID, WF, ACC)                                               \
    do {                                                                       \
        const float wf = (WF);                                                 \
        const half8_t a = *(const half8_t*)(pv + (unsigned)((SRCID) - offPrev) * (TB * 2)); \
        _Pragma("unroll")                                                      \
        for (int k = 0; k < 8; ++k)                                            \
            ACC[k] = fmaf((float)a[k], wf, ACC[k]);                            \
    } while (0)

    // Layers 1..4 (512 nodes): thread (n, h) does 16 of node n's 32 edges.
#pragma unroll
    for (int l = 0; l < 4; ++l) {
        const char* pv = (const char*)prev;
        float8_t acc = {0.f, 0.f, 0.f, 0.f, 0.f, 0.f, 0.f, 0.f};
        if (PACKED) {
            const int4* rl = rp + l * 4096;
#pragma unroll
            for (int c = 0; c < 4; ++c) {
                const int4 r4 = rl[base + c * 128];
                EDGE(r4.x, acc);
                EDGE(r4.y, acc);
                EDGE(r4.z, acc);
                EDGE(r4.w, acc);
            }
        } else {
            const int e0 = l * 16384;
            const int offPrev = (l == 0) ? 0 : (256 + (l - 1) * 512);
            const int ebase = e0 + n * 32 + h * 16;
#pragma unroll
            for (int c = 0; c < 4; ++c) {
                const int4   s4 = *(const int4*)(src + ebase + c * 4);
                const float4 w4 = *(const float4*)(w + ebase + c * 4);
                EDGE_RAW(s4.x, w4.x, acc);
                EDGE_RAW(s4.y, w4.y, acc);
                EDGE_RAW(s4.z, w4.z, acc);
                EDGE_RAW(s4.w, w4.w, acc);
            }
        }
        if (h == 1) {
            float* d = scratch + n * 12;
            *(float4*)(d + 0) = make_float4(acc[0], acc[1], acc[2], acc[3]);
            *(float4*)(d + 4) = make_float4(acc[4], acc[5], acc[6], acc[7]);
        }
        __syncthreads();
        if (h == 0) {
            const float* s = scratch + n * 12;
            const float4 p0 = *(const float4*)(s + 0);
            const float4 p1 = *(const float4*)(s + 4);
            half8_t r;
            r[0] = (_Float16)sigmoidf(acc[0] + p0.x);
            r[1] = (_Float16)sigmoidf(acc[1] + p0.y);
            r[2] = (_Float16)sigmoidf(acc[2] + p0.z);
            r[3] = (_Float16)sigmoidf(acc[3] + p0.w);
            r[4] = (_Float16)sigmoidf(acc[4] + p1.x);
            r[5] = (_Float16)sigmoidf(acc[5] + p1.y);
            r[6] = (_Float16)sigmoidf(acc[6] + p1.z);
            r[7] = (_Float16)sigmoidf(acc[7] + p1.w);
            *(half8_t*)(cur + n * TB) = r;
        }
        __syncthreads();
        _Float16* t = prev; prev = cur; cur = t;
    }

    // Layer 5: 64 nodes x 32 edges; threads 0..511: t = c*64+n handles 4 edges
    // of node n (chunk c). Partials -> scratch (stride 12), then reduce.
    if (tid < 512) {
        const char* pv = (const char*)prev;
        float8_t acc = {0.f, 0.f, 0.f, 0.f, 0.f, 0.f, 0.f, 0.f};
        if (PACKED) {
            const int4 r4 = rp[16384 + tid];
            EDGE(r4.x, acc);
            EDGE(r4.y, acc);
            EDGE(r4.z, acc);
            EDGE(r4.w, acc);
        } else {
            const int nn = tid & 63, c = tid >> 6;
            const int offPrev = 1792;
            const int eb = 65536 + nn * 32 + c * 4;
            const int4   s4 = *(const int4*)(src + eb);
            const float4 w4 = *(const float4*)(w + eb);
            EDGE_RAW(s4.x, w4.x, acc);
            EDGE_RAW(s4.y, w4.y, acc);
            EDGE_RAW(s4.z, w4.z, acc);
            EDGE_RAW(s4.w, w4.w, acc);
        }
        float* d = scratch + tid * 12;
        *(float4*)(d + 0) = make_float4(acc[0], acc[1], acc[2], acc[3]);
        *(float4*)(d + 4) = make_float4(acc[4], acc[5], acc[6], acc[7]);
    }
    __syncthreads();

    // Reduce 8 chunk-partials per (node, batch row); threads 0..511,
    // n = tid&63 (coalesced stores), b = tid>>6.
    if (tid < 512) {
        const int nn = tid & 63;
        const int b  = tid >> 6;
        float s = 0.f;
#pragma unroll
        for (int c = 0; c < 8; ++c)
            s += scratch[(c * 64 + nn) * 12 + b];
        out[(size_t)(batch0 + b) * 64 + nn] = sigmoidf(s);
    }
#undef EDGE
#undef EDGE_RAW
}

extern "C" void kernel_launch(void* const* d_in, const int* in_sizes, int n_in,
                              void* d_out, int out_size, void* d_ws, size_t ws_size,
                              hipStream_t stream)
{
    const float* x   = (const float*)d_in[0];
    const float* w   = (const float*)d_in[1];
    const int*   src = (const int*)d_in[2];
    float* out = (float*)d_out;

    const int batch = in_sizes[0] / 256;   // 2048
    const int grid  = batch / TB;          // 256

    unsigned* rec = (unsigned*)d_ws;

    if (ws_size >= (size_t)E_TOT * 4) {
        pack_edges<<<(E_TOT + 255) / 256, 256, 0, stream>>>(src, w, rec);
        neat_fwd<true><<<grid, BLOCK, 0, stream>>>(x, w, src, (const int4*)rec, out);
    } else {
        neat_fwd<false><<<grid, BLOCK, 0, stream>>>(x, w, src, (const int4*)rec, out);
    }
}

// Round 6
// 21.138 us; speedup vs baseline: 1.1104x; 1.1104x over previous
//
#include <hip/hip_runtime.h>
#include <hip/hip_fp16.h>

// NEAT sparse MLP fwd. LAYER_SIZES=[256,512,512,512,512,64], FAN_IN=32, BATCH=2048.
// OFFSETS=[0,256,768,1280,1792,2304,2368]; E_TOT=67584.
//
// R6 = R4 fwd structure (best so far) + bank-conflict-aware edge scheduling.
// LDS acts layout [node][8]f16 = 16 B/node -> node's data lives in bank-group
// node%8. Random gathers draw 64 lanes over 8 groups WITH replacement
// (E[max]~12-14 lanes/group); since + is commutative we permute each node's 32
// edges so wave-step t at lane l reads class (t+l)&7 -> exactly 8 lanes/group
// per ds_read_b128 (minimum service time). Deterministic parallel scheduler in
// pack kernel (bitplane masks, no serial greedy, OR-atomics only).

typedef _Float16 half8_t  __attribute__((ext_vector_type(8)));
typedef float    float8_t __attribute__((ext_vector_type(8)));

constexpr int TB    = 8;
constexpr int BLOCK = 512;
constexpr int E_TOT = 67584;

__device__ __forceinline__ unsigned nth_set_bit(unsigned m, int o)
{
    // index of the (o+1)-th set bit of m (o zero-based); caller guarantees it exists.
    unsigned p = 0, r = (unsigned)o + 1, c;
    c = __popc(m & 0xFFFFu); if (r > c) { r -= c; m >>= 16; p += 16; }
    c = __popc(m & 0xFFu);   if (r > c) { r -= c; m >>= 8;  p += 8;  }
    c = __popc(m & 0xFu);    if (r > c) { r -= c; m >>= 4;  p += 4;  }
    c = __popc(m & 0x3u);    if (r > c) { r -= c; m >>= 2;  p += 2;  }
    c = __popc(m & 0x1u);    if (r > c) { p += 1; }
    return p;
}

__device__ __forceinline__ unsigned rep_bits(int k)
{
    // first k of bits {0,8,16,24}
    unsigned v = 0;
    v = (k > 0) ? 0x00000001u : v;
    v = (k > 1) ? 0x00000101u : v;
    v = (k > 2) ? 0x00010101u : v;
    v = (k > 3) ? 0x01010101u : v;
    return v;
}

// One thread per edge. Blocks of 256 = 8 whole nodes (node edge ranges are
// 32-aligned, 65536 & block size align). Grid = E_TOT/256 = 264 exactly.
__global__ __launch_bounds__(256) void pack_sched(const int* __restrict__ src,
                                                  const float* __restrict__ w,
                                                  unsigned* __restrict__ rec)
{
    __shared__ unsigned pl[8][4];   // 3 class bitplanes per node-slot (+pad)

    const int t  = blockIdx.x * 256 + threadIdx.x;   // global edge id
    const int j  = t & 31;                           // edge index within node
    const int nb = threadIdx.x >> 5;                 // node slot in block

    int L, n, offPrev, lane;
    if (t < 65536) {
        L = t >> 14;
        offPrev = (L == 0) ? 0 : (256 + (L - 1) * 512);
        n = (t >> 5) & 511;
        lane = n & 63;
    } else {
        L = 4; offPrev = 1792;
        n = (t - 65536) >> 5;
        lane = n;
    }

    if (threadIdx.x < 32)
        ((unsigned*)pl)[threadIdx.x] = 0;
    __syncthreads();

    const int      s    = src[t] - offPrev;            // 0..511 local src node
    const unsigned c    = (unsigned)s & 7u;            // bank-group class
    const unsigned vrec = ((unsigned)(s << 4)) |
                          ((unsigned)__half_as_ushort(__float2half(w[t])) << 16);

    atomicOr(&pl[nb][0], (c & 1u) << j);
    atomicOr(&pl[nb][1], ((c >> 1) & 1u) << j);
    atomicOr(&pl[nb][2], ((c >> 2) & 1u) << j);
    __syncthreads();

    const unsigned p0 = pl[nb][0], p1 = pl[nb][1], p2 = pl[nb][2];

    // taken-slot mask + overflow-rank prefix over classes < c
    unsigned taken = 0;
    int ovfBefore = 0;
#pragma unroll
    for (int cc = 0; cc < 8; ++cc) {
        const unsigned m = ((cc & 1) ? p0 : ~p0) & ((cc & 2) ? p1 : ~p1) & ((cc & 4) ? p2 : ~p2);
        const int cnt = __popc(m);
        const int k   = cnt < 4 ? cnt : 4;
        taken |= rep_bits(k) << ((cc - lane) & 7);
        ovfBefore += ((unsigned)cc < c) ? (cnt > 4 ? cnt - 4 : 0) : 0;
    }

    const unsigned mc = ((c & 1) ? p0 : ~p0) & ((c & 2) ? p1 : ~p1) & ((c & 4) ? p2 : ~p2);
    const int q = __popc(mc & ((1u << j) - 1u));   // my rank within class (j order)

    int t2;
    if (q < 4) {
        t2 = q * 8 + (int)((c - (unsigned)lane) & 7u);
    } else {
        t2 = (int)nth_set_bit(~taken, ovfBefore + (q - 4));
    }

    int pos;
    if (L < 4) {
        const int g = n >> 6, i = n & 63, cch = t2 >> 2, qq = t2 & 3;
        pos = (L << 14) + (((g * 8 + cch) * 64 + i) << 2) + qq;
    } else {
        const int cch = t2 >> 2, qq = t2 & 3;
        pos = 65536 + ((cch * 64 + n) << 2) + qq;
    }
    rec[pos] = vrec;
}

__device__ __forceinline__ float sigmoidf(float s)
{
    return __fdividef(1.0f, 1.0f + __expf(-s));
}

template<bool PACKED>
__global__ __launch_bounds__(BLOCK) void neat_fwd(
    const float* __restrict__ x,
    const float* __restrict__ w,
    const int*   __restrict__ src,
    const int4*  __restrict__ rp,      // packed records as int4 (4 edges)
    float*       __restrict__ out)
{
    __shared__ __align__(16) _Float16 bufA[512 * TB];   // 8 KB
    __shared__ __align__(16) _Float16 bufB[512 * TB];   // 8 KB
    __shared__ float l5p[512 * 9];                      // 18 KB, stride-9 pad

    const int tid    = threadIdx.x;
    const int batch0 = blockIdx.x * TB;

    // Stage input layer as f16 [node][8]: 256 nodes x 8 rows.
    {
        const int r  = tid >> 6;          // 0..7
        const int c4 = (tid & 63) * 4;    // node base
        const float4 v = *(const float4*)(x + (size_t)(batch0 + r) * 256 + c4);
        bufA[(c4 + 0) * TB + r] = (_Float16)v.x;
        bufA[(c4 + 1) * TB + r] = (_Float16)v.y;
        bufA[(c4 + 2) * TB + r] = (_Float16)v.z;
        bufA[(c4 + 3) * TB + r] = (_Float16)v.w;
    }
    __syncthreads();

    _Float16* prev = bufA;
    _Float16* cur  = bufB;

    const int base = (tid >> 6) * 512 + (tid & 63);   // int4 index within a 512-layer

#define EDGE(RR, ACC)                                                          \
    do {                                                                       \
        const unsigned rr = (unsigned)(RR);                                    \
        const float wf = __half2float(__ushort_as_half((unsigned short)(rr >> 16))); \
        const half8_t a = *(const half8_t*)(pv + (rr & 0xffffu));              \
        _Pragma("unroll")                                                      \
        for (int k = 0; k < 8; ++k)                                            \
            ACC[k] = fmaf((float)a[k], wf, ACC[k]);                            \
    } while (0)

#define EDGE_RAW(SRCID, WF, ACC)                                               \
    do {                                                                       \
        const float wf = (WF);                                                 \
        const half8_t a = *(const half8_t*)(pv + (unsigned)((SRCID) - offPrev) * (TB * 2)); \
        _Pragma("unroll")                                                      \
        for (int k = 0; k < 8; ++k)                                            \
            ACC[k] = fmaf((float)a[k], wf, ACC[k]);                            \
    } while (0)

    // Layers 1..4 (512 nodes each): thread == node.
#pragma unroll
    for (int l = 0; l < 4; ++l) {
        const char* pv = (const char*)prev;
        float8_t acc = {0.f, 0.f, 0.f, 0.f, 0.f, 0.f, 0.f, 0.f};
        if (PACKED) {
            const int4* rl = rp + l * 4096;
#pragma unroll
            for (int c = 0; c < 8; ++c) {
                const int4 r4 = rl[base + c * 64];
                EDGE(r4.x, acc);
                EDGE(r4.y, acc);
                EDGE(r4.z, acc);
                EDGE(r4.w, acc);
            }
        } else {
            const int e0 = l * 16384;
            const int offPrev = (l == 0) ? 0 : (256 + (l - 1) * 512);
            const int ebase = e0 + tid * 32;
#pragma unroll
            for (int c = 0; c < 8; ++c) {
                const int4   s4 = *(const int4*)(src + ebase + c * 4);
                const float4 w4 = *(const float4*)(w + ebase + c * 4);
                EDGE_RAW(s4.x, w4.x, acc);
                EDGE_RAW(s4.y, w4.y, acc);
                EDGE_RAW(s4.z, w4.z, acc);
                EDGE_RAW(s4.w, w4.w, acc);
            }
        }
        half8_t r;
#pragma unroll
        for (int k = 0; k < 8; ++k)
            r[k] = (_Float16)sigmoidf(acc[k]);
        *(half8_t*)(cur + tid * TB) = r;
        __syncthreads();
        _Float16* t = prev; prev = cur; cur = t;
    }

    // Layer 5: 64 nodes x 32 edges; thread tid = c*64+n handles 4 edges of
    // node n (chunk c). Partial float8 -> padded LDS, then reduce.
    {
        const char* pv = (const char*)prev;
        float8_t acc = {0.f, 0.f, 0.f, 0.f, 0.f, 0.f, 0.f, 0.f};
        if (PACKED) {
            const int4 r4 = rp[16384 + tid];
            EDGE(r4.x, acc);
            EDGE(r4.y, acc);
            EDGE(r4.z, acc);
            EDGE(r4.w, acc);
        } else {
            const int n = tid & 63, c = tid >> 6;
            const int offPrev = 1792;
            const int eb = 65536 + n * 32 + c * 4;
            const int4   s4 = *(const int4*)(src + eb);
            const float4 w4 = *(const float4*)(w + eb);
            EDGE_RAW(s4.x, w4.x, acc);
            EDGE_RAW(s4.y, w4.y, acc);
            EDGE_RAW(s4.z, w4.z, acc);
            EDGE_RAW(s4.w, w4.w, acc);
        }
        float* dst = l5p + tid * 9;
#pragma unroll
        for (int k = 0; k < 8; ++k)
            dst[k] = acc[k];
    }
    __syncthreads();

    // Reduce 8 chunk-partials per (node, batch row) and store.
    {
        const int n = tid & 63;
        const int b = tid >> 6;
        float s = 0.f;
#pragma unroll
        for (int c = 0; c < 8; ++c)
            s += l5p[(c * 64 + n) * 9 + b];
        out[(size_t)(batch0 + b) * 64 + n] = sigmoidf(s);
    }
#undef EDGE
#undef EDGE_RAW
}

extern "C" void kernel_launch(void* const* d_in, const int* in_sizes, int n_in,
                              void* d_out, int out_size, void* d_ws, size_t ws_size,
                              hipStream_t stream)
{
    const float* x   = (const float*)d_in[0];
    const float* w   = (const float*)d_in[1];
    const int*   src = (const int*)d_in[2];
    float* out = (float*)d_out;

    const int batch = in_sizes[0] / 256;   // 2048
    const int grid  = batch / TB;          // 256

    unsigned* rec = (unsigned*)d_ws;

    if (ws_size >= (size_t)E_TOT * 4) {
        pack_sched<<<E_TOT / 256, 256, 0, stream>>>(src, w, rec);
        neat_fwd<true><<<grid, BLOCK, 0, stream>>>(x, w, src, (const int4*)rec, out);
    } else {
        neat_fwd<false><<<grid, BLOCK, 0, stream>>>(x, w, src, (const int4*)rec, out);
    }
}